// Round 12
// baseline (480.912 us; speedup 1.0000x reference)
//
#include <hip/hip_runtime.h>
#include <hip/hip_bf16.h>

#define N_NODES 100000
#define N_EDGES 1600000
#define PAD 64                             // padded CSR slots/node (max deg ~45, P(>64)~1e-10)

#define FILL_BLOCKS 6250
#define CVTX_BLOCKS 12500
#define CVTW_BLOCKS 320

typedef unsigned short ushort_t;
typedef unsigned int uint_t;
typedef __bf16 bf16x8 __attribute__((ext_vector_type(8)));
typedef float f32x4 __attribute__((ext_vector_type(4)));

__device__ __forceinline__ float bf2f_lo(uint_t u) {
    union { uint_t i; float f; } v; v.i = u << 16; return v.f;
}
__device__ __forceinline__ float bf2f_hi(uint_t u) {
    union { uint_t i; float f; } v; v.i = u & 0xffff0000u; return v.f;
}
__device__ __forceinline__ ushort_t f2bf(float f) {
    uint_t x = __float_as_uint(f);
    uint_t r = (x + 0x7fffu + ((x >> 16) & 1u)) >> 16;
    return (ushort_t)r;
}

#define UNPACK4(v) \
    acc[0] += bf2f_lo(v.x); acc[1] += bf2f_hi(v.x); \
    acc[2] += bf2f_lo(v.y); acc[3] += bf2f_hi(v.y); \
    acc[4] += bf2f_lo(v.z); acc[5] += bf2f_hi(v.z); \
    acc[6] += bf2f_lo(v.w); acc[7] += bf2f_hi(v.w);

// ======== fused pre-pass: fill | cvt_x | cvt_w (one launch) ========
// Fill blocks are atomic-latency-bound (low BW); cvt_x blocks are
// streaming-BW-bound -> they overlap on disjoint resources.
// cursor must be memset(0) before this kernel; cursor[n] ends as degree(n).
// wt0/wt1: [128 outcol][256 k] (k 0..127 = W_self, 128..255 = W_neigh)
// wt2:     [128 outcol][128 k] (outcol 0..63 = W_self2, 64..127 = W_neigh2)

__global__ __launch_bounds__(256) void k_pre(const int* __restrict__ src, const int* __restrict__ dst,
                                             int* __restrict__ cursor, int* __restrict__ colp,
                                             const float* __restrict__ x, ushort_t* __restrict__ h,
                                             const float* __restrict__ ws0, const float* __restrict__ wn0,
                                             const float* __restrict__ ws1, const float* __restrict__ wn1,
                                             const float* __restrict__ ws2, const float* __restrict__ wn2,
                                             ushort_t* __restrict__ wt0, ushort_t* __restrict__ wt1,
                                             ushort_t* __restrict__ wt2) {
    int b = blockIdx.x;
    if (b < FILL_BLOCKS) {
        int e = b * 256 + threadIdx.x;          // E == 6250*256 exactly
        int d = dst[e];
        int s = src[e];
        int r = atomicAdd(&cursor[d], 1);
        colp[d * PAD + r] = s;
    } else if (b < FILL_BLOCKS + CVTX_BLOCKS) {
        int i = ((b - FILL_BLOCKS) * 256 + threadIdx.x) * 4;
        float4 v = *(const float4*)(x + i);
        uint2 o;
        o.x = (uint_t)f2bf(v.x) | ((uint_t)f2bf(v.y) << 16);
        o.y = (uint_t)f2bf(v.z) | ((uint_t)f2bf(v.w) << 16);
        *(uint2*)(h + i) = o;
    } else {
        int idx = (b - FILL_BLOCKS - CVTX_BLOCKS) * 256 + threadIdx.x;  // 0..81919
        if (idx < 65536) {
            const float* Ws = (idx < 32768) ? ws0 : ws1;
            const float* Wn = (idx < 32768) ? wn0 : wn1;
            ushort_t* Wt    = (idx < 32768) ? wt0 : wt1;
            int local = idx & 32767;
            int n = local >> 8, k = local & 255;
            float v = (k < 128) ? Ws[k * 128 + n] : Wn[(k - 128) * 128 + n];
            Wt[n * 256 + k] = f2bf(v);
        } else {
            int local = idx - 65536;                // 16384 elems
            int n = local >> 7, k = local & 127;
            float v = (n < 64) ? ws2[k * 64 + n] : wn2[k * 64 + (n - 64)];
            wt2[n * 128 + k] = f2bf(v);
        }
    }
}

// ======== gather-mean, 128-wide rows, dwordx4: 4 edges/load, 16 in flight ====
// lane = j*16 + d: j = edge slot (0..3), d = 16B chunk (feats d*8..d*8+7).

__global__ __launch_bounds__(256) void k_agg(const ushort_t* __restrict__ h,
                                             const int* __restrict__ cur,
                                             const int* __restrict__ colp,
                                             ushort_t* __restrict__ out) {
    const int node = blockIdx.x * 4 + (threadIdx.x >> 6);   // 25000*4 == N
    const int lane = threadIdx.x & 63;
    const int j = lane >> 4;
    const int d = lane & 15;
    const int beg = node * PAD;
    const int deg = cur[node];
    const int end = beg + deg;
    float acc[8];
#pragma unroll
    for (int k = 0; k < 8; ++k) acc[k] = 0.f;

    int i = beg;
    for (; i + 16 <= end; i += 16) {        // 4 quads in flight
        int c0 = colp[i + j];
        int c1 = colp[i + 4 + j];
        int c2 = colp[i + 8 + j];
        int c3 = colp[i + 12 + j];
        uint4 v0 = *(const uint4*)(h + (size_t)c0 * 128 + d * 8);
        uint4 v1 = *(const uint4*)(h + (size_t)c1 * 128 + d * 8);
        uint4 v2 = *(const uint4*)(h + (size_t)c2 * 128 + d * 8);
        uint4 v3 = *(const uint4*)(h + (size_t)c3 * 128 + d * 8);
        UNPACK4(v0) UNPACK4(v1) UNPACK4(v2) UNPACK4(v3)
    }
    if (i + 8 <= end) {
        int c0 = colp[i + j];
        int c1 = colp[i + 4 + j];
        uint4 v0 = *(const uint4*)(h + (size_t)c0 * 128 + d * 8);
        uint4 v1 = *(const uint4*)(h + (size_t)c1 * 128 + d * 8);
        UNPACK4(v0) UNPACK4(v1)
        i += 8;
    }
    if (i + 4 <= end) {
        int c0 = colp[i + j];
        uint4 v0 = *(const uint4*)(h + (size_t)c0 * 128 + d * 8);
        UNPACK4(v0)
        i += 4;
    }
    int rem = end - i;                      // 0..3
    if (rem > 0) {
        int idx = i + (j < rem ? j : 0);    // clamped dup -> same line, L1 hit
        int c0 = colp[idx];
        uint4 v0 = *(const uint4*)(h + (size_t)c0 * 128 + d * 8);
        if (j < rem) { UNPACK4(v0) }
    }
#pragma unroll
    for (int k = 0; k < 8; ++k) {
        acc[k] += __shfl_xor(acc[k], 16);
        acc[k] += __shfl_xor(acc[k], 32);
    }
    float inv = (deg > 0) ? 1.0f / (float)deg : 0.f;
    if (lane < 16) {
        uint4 o;
        o.x = (uint_t)f2bf(acc[0] * inv) | ((uint_t)f2bf(acc[1] * inv) << 16);
        o.y = (uint_t)f2bf(acc[2] * inv) | ((uint_t)f2bf(acc[3] * inv) << 16);
        o.z = (uint_t)f2bf(acc[4] * inv) | ((uint_t)f2bf(acc[5] * inv) << 16);
        o.w = (uint_t)f2bf(acc[6] * inv) | ((uint_t)f2bf(acc[7] * inv) << 16);
        *(uint4*)(out + (size_t)node * 128 + d * 8) = o;
    }
}

// ======== gather-mean-add, 64-wide bf16 rows (128B): 8 edges/load ========
// lane = j*8 + d: j = edge slot (0..7), d = 16B chunk.

__global__ __launch_bounds__(256) void k_agg_add64(const ushort_t* __restrict__ g,
                                                   const int* __restrict__ cur,
                                                   const int* __restrict__ colp,
                                                   float* __restrict__ out) {
    const int node = blockIdx.x * 4 + (threadIdx.x >> 6);
    const int lane = threadIdx.x & 63;
    const int j = lane >> 3;
    const int d = lane & 7;
    const int beg = node * PAD;
    const int deg = cur[node];
    const int end = beg + deg;
    float acc[8];
#pragma unroll
    for (int k = 0; k < 8; ++k) acc[k] = 0.f;

    int i = beg;
    for (; i + 16 <= end; i += 16) {        // 2 in flight
        int c0 = colp[i + j];
        int c1 = colp[i + 8 + j];
        uint4 v0 = *(const uint4*)(g + (size_t)c0 * 64 + d * 8);
        uint4 v1 = *(const uint4*)(g + (size_t)c1 * 64 + d * 8);
        UNPACK4(v0) UNPACK4(v1)
    }
    if (i + 8 <= end) {
        int c0 = colp[i + j];
        uint4 v0 = *(const uint4*)(g + (size_t)c0 * 64 + d * 8);
        UNPACK4(v0)
        i += 8;
    }
    int rem = end - i;                      // 0..7
    if (rem > 0) {
        int idx = i + (j < rem ? j : 0);
        int c0 = colp[idx];
        uint4 v0 = *(const uint4*)(g + (size_t)c0 * 64 + d * 8);
        if (j < rem) { UNPACK4(v0) }
    }
#pragma unroll
    for (int k = 0; k < 8; ++k) {
        acc[k] += __shfl_xor(acc[k], 8);
        acc[k] += __shfl_xor(acc[k], 16);
        acc[k] += __shfl_xor(acc[k], 32);
    }
    float inv = (deg > 0) ? 1.0f / (float)deg : 0.f;
    if (lane < 8) {
        float* p = out + (size_t)node * 64 + d * 8;
        float4 p0 = *(float4*)p;
        float4 p1 = *(float4*)(p + 4);
        p0.x += acc[0] * inv; p0.y += acc[1] * inv;
        p0.z += acc[2] * inv; p0.w += acc[3] * inv;
        p1.x += acc[4] * inv; p1.y += acc[5] * inv;
        p1.z += acc[6] * inv; p1.w += acc[7] * inv;
        *(float4*)p = p0;
        *(float4*)(p + 4) = p1;
    }
}

// ======== dual-GEMM + bias + ReLU (layers 0,1): K=256, LDS weights ========
// 512 threads (8 waves)/block: 67.6KB LDS -> 2 blocks/CU = 16 waves/CU.

__global__ __launch_bounds__(512) void k_gemm(const ushort_t* __restrict__ hs,
                                              const ushort_t* __restrict__ hn,
                                              const ushort_t* __restrict__ wt,
                                              const float* __restrict__ bias,
                                              ushort_t* __restrict__ hout) {
    constexpr int NT = 8;
    __shared__ ushort_t lds_w[128][264];   // pitch 528B -> 2-way (free) conflicts
    const int t = threadIdx.x;
    for (int c = t; c < 128 * 32; c += 512) {
        int r = c >> 5, o = c & 31;
        *(uint4*)(&lds_w[r][o * 8]) = *(const uint4*)(wt + r * 256 + o * 8);
    }
    __syncthreads();

    int wid = t >> 6, lane = t & 63;
    int row0 = blockIdx.x * 128 + wid * 16;
    int arow = row0 + (lane & 15);
    if (arow >= N_NODES) arow = N_NODES - 1;
    int hi = lane >> 4;   // 0..3

    f32x4 acc[NT];
#pragma unroll
    for (int n = 0; n < NT; n++) acc[n] = (f32x4){0.f, 0.f, 0.f, 0.f};

#pragma unroll
    for (int kk = 0; kk < 8; kk++) {
        const ushort_t* hp = (kk < 4) ? hs : hn;
        int kloc = (kk & 3) * 32 + hi * 8;
        bf16x8 a = *(const bf16x8*)(hp + (size_t)arow * 128 + kloc);
#pragma unroll
        for (int n = 0; n < NT; n++) {
            bf16x8 b = *(const bf16x8*)(&lds_w[n * 16 + (lane & 15)][kk * 32 + hi * 8]);
            acc[n] = __builtin_amdgcn_mfma_f32_16x16x32_bf16(a, b, acc[n], 0, 0, 0);
        }
    }

#pragma unroll
    for (int n = 0; n < NT; n++) {
        int colc = n * 16 + (lane & 15);
        float bv = bias[colc];
#pragma unroll
        for (int j = 0; j < 4; j++) {
            int row = row0 + hi * 4 + j;
            if (row < N_NODES) {
                float v = acc[n][j] + bv;
                v = v > 0.f ? v : 0.f;
                hout[(size_t)row * 128 + colc] = f2bf(v);
            }
        }
    }
}

// ======== layer-2 GEMM: K=128, [s2=h@Ws2+b2 -> f32 d_out | g2=h@Wn2 -> bf16] ==

__global__ __launch_bounds__(512) void k_gemm2(const ushort_t* __restrict__ hs,
                                               const ushort_t* __restrict__ wt,
                                               const float* __restrict__ bias,
                                               float* __restrict__ fout,
                                               ushort_t* __restrict__ g2) {
    constexpr int NT = 8;
    __shared__ ushort_t lds_w[128][136];   // 34.8KB -> 4 blocks/CU
    const int t = threadIdx.x;
    for (int c = t; c < 128 * 16; c += 512) {
        int r = c >> 4, o = c & 15;
        *(uint4*)(&lds_w[r][o * 8]) = *(const uint4*)(wt + r * 128 + o * 8);
    }
    __syncthreads();

    int wid = t >> 6, lane = t & 63;
    int row0 = blockIdx.x * 128 + wid * 16;
    int arow = row0 + (lane & 15);
    if (arow >= N_NODES) arow = N_NODES - 1;
    int hi = lane >> 4;   // 0..3

    f32x4 acc[NT];
#pragma unroll
    for (int n = 0; n < NT; n++) acc[n] = (f32x4){0.f, 0.f, 0.f, 0.f};

#pragma unroll
    for (int kk = 0; kk < 4; kk++) {
        bf16x8 a = *(const bf16x8*)(hs + (size_t)arow * 128 + kk * 32 + hi * 8);
#pragma unroll
        for (int n = 0; n < NT; n++) {
            bf16x8 b = *(const bf16x8*)(&lds_w[n * 16 + (lane & 15)][kk * 32 + hi * 8]);
            acc[n] = __builtin_amdgcn_mfma_f32_16x16x32_bf16(a, b, acc[n], 0, 0, 0);
        }
    }

#pragma unroll
    for (int n = 0; n < NT; n++) {
        int colc = n * 16 + (lane & 15);    // 0..127
#pragma unroll
        for (int j = 0; j < 4; j++) {
            int row = row0 + hi * 4 + j;
            if (row < N_NODES) {
                float v = acc[n][j];
                if (n < 4) fout[(size_t)row * 64 + colc] = v + bias[colc];
                else       g2[(size_t)row * 64 + (colc - 64)] = f2bf(v);
            }
        }
    }
}

// ======== launch ========

extern "C" void kernel_launch(void* const* d_in, const int* in_sizes, int n_in,
                              void* d_out, int out_size, void* d_ws, size_t ws_size,
                              hipStream_t stream) {
    const float* x   = (const float*)d_in[0];
    const int*   src = (const int*)d_in[1];
    const int*   dst = (const int*)d_in[2];
    const float* ws0 = (const float*)d_in[3];
    const float* wn0 = (const float*)d_in[4];
    const float* b0  = (const float*)d_in[5];
    const float* ws1 = (const float*)d_in[6];
    const float* wn1 = (const float*)d_in[7];
    const float* b1  = (const float*)d_in[8];
    const float* ws2 = (const float*)d_in[9];
    const float* wn2 = (const float*)d_in[10];
    const float* b2  = (const float*)d_in[11];

    char* ws = (char*)d_ws;
    size_t o = 0;
    auto alloc = [&](size_t bytes) { size_t r = o; o = (o + bytes + 255) & ~(size_t)255; return r; };
    int* cursor     = (int*)(ws + alloc((size_t)N_NODES * 4));
    int* colp       = (int*)(ws + alloc((size_t)N_NODES * PAD * 4));   // 25.6MB padded CSR
    ushort_t* wt0   = (ushort_t*)(ws + alloc(128 * 256 * 2));
    ushort_t* wt1   = (ushort_t*)(ws + alloc(128 * 256 * 2));
    ushort_t* wt2   = (ushort_t*)(ws + alloc(128 * 128 * 2));
    ushort_t* hA    = (ushort_t*)(ws + alloc((size_t)N_NODES * 128 * 2));
    ushort_t* hB    = (ushort_t*)(ws + alloc((size_t)N_NODES * 128 * 2));
    ushort_t* hN    = (ushort_t*)(ws + alloc((size_t)N_NODES * 128 * 2));
    (void)ws_size;

    (void)hipMemsetAsync(cursor, 0, (size_t)N_NODES * 4, stream);
    k_pre<<<FILL_BLOCKS + CVTX_BLOCKS + CVTW_BLOCKS, 256, 0, stream>>>(
        src, dst, cursor, colp, x, hA, ws0, wn0, ws1, wn1, ws2, wn2, wt0, wt1, wt2);

    const int AGG_GRID  = N_NODES / 4;             // 25000
    const int GEMM_GRID = (N_NODES + 127) / 128;   // 782

    // layers 0,1: aggregate-then-project
    k_agg<<<AGG_GRID, 256, 0, stream>>>(hA, cursor, colp, hN);
    k_gemm<<<GEMM_GRID, 512, 0, stream>>>(hA, hN, wt0, b0, hB);
    k_agg<<<AGG_GRID, 256, 0, stream>>>(hB, cursor, colp, hN);
    k_gemm<<<GEMM_GRID, 512, 0, stream>>>(hB, hN, wt1, b1, hA);
    // layer 2: project-then-aggregate (64-wide gather)
    k_gemm2<<<GEMM_GRID, 512, 0, stream>>>(hA, wt2, b2, (float*)d_out, hN);
    k_agg_add64<<<AGG_GRID, 256, 0, stream>>>(hN, cursor, colp, (float*)d_out);
}

// Round 15
// 406.445 us; speedup vs baseline: 1.1832x; 1.1832x over previous
//
#include <hip/hip_runtime.h>
#include <hip/hip_bf16.h>

#define N_NODES 100000
#define N_EDGES 1600000
#define PAD 64                             // padded CSR slots/node (max deg ~45, P(>64)~1e-10)
#define FILL_SLICES 8
#define SLICE_NN (N_NODES / FILL_SLICES)   // 12500
#define FILL_CHUNKS 256
#define CHUNK_E (N_EDGES / FILL_CHUNKS)    // 6250

#define FILL_BLOCKS (FILL_CHUNKS * FILL_SLICES)   // 2048
#define CVTX_BLOCKS 12500
#define CVTW_BLOCKS 320

typedef unsigned short ushort_t;
typedef unsigned int uint_t;
typedef __bf16 bf16x8 __attribute__((ext_vector_type(8)));
typedef float f32x4 __attribute__((ext_vector_type(4)));

__device__ __forceinline__ float bf2f_lo(uint_t u) {
    union { uint_t i; float f; } v; v.i = u << 16; return v.f;
}
__device__ __forceinline__ float bf2f_hi(uint_t u) {
    union { uint_t i; float f; } v; v.i = u & 0xffff0000u; return v.f;
}
__device__ __forceinline__ ushort_t f2bf(float f) {
    uint_t x = __float_as_uint(f);
    uint_t r = (x + 0x7fffu + ((x >> 16) & 1u)) >> 16;
    return (ushort_t)r;
}

#define UNPACK4(v) \
    acc[0] += bf2f_lo(v.x); acc[1] += bf2f_hi(v.x); \
    acc[2] += bf2f_lo(v.y); acc[3] += bf2f_hi(v.y); \
    acc[4] += bf2f_lo(v.z); acc[5] += bf2f_hi(v.z); \
    acc[6] += bf2f_lo(v.w); acc[7] += bf2f_hi(v.w);

// ======== fused pre-pass: SLICED fill | cvt_x | cvt_w (one launch) ========
// Fill keeps R11's dst-range slicing (slice = b&7): colp window 3.2MB/slice
// stays L2-merged. Fill blocks are atomic-latency-bound; cvt_x blocks are
// streaming-BW-bound -> overlap on disjoint resources.
// cursor must be memset(0) before this kernel; cursor[n] ends as degree(n).
// wt0/wt1: [128 outcol][256 k] (k 0..127 = W_self, 128..255 = W_neigh)
// wt2:     [128 outcol][128 k] (outcol 0..63 = W_self2, 64..127 = W_neigh2)

__global__ __launch_bounds__(256) void k_pre(const int* __restrict__ src, const int* __restrict__ dst,
                                             int* __restrict__ cursor, int* __restrict__ colp,
                                             const float* __restrict__ x, ushort_t* __restrict__ h,
                                             const float* __restrict__ ws0, const float* __restrict__ wn0,
                                             const float* __restrict__ ws1, const float* __restrict__ wn1,
                                             const float* __restrict__ ws2, const float* __restrict__ wn2,
                                             ushort_t* __restrict__ wt0, ushort_t* __restrict__ wt1,
                                             ushort_t* __restrict__ wt2) {
    int b = blockIdx.x;
    if (b < FILL_BLOCKS) {
        int slice = b & (FILL_SLICES - 1);
        int chunk = b >> 3;
        int lo = slice * SLICE_NN, hi = lo + SLICE_NN;
        int base = chunk * CHUNK_E;
        for (int e = base + threadIdx.x; e < base + CHUNK_E; e += 256) {
            int d = dst[e];
            if (d >= lo && d < hi) {
                int s = src[e];
                int r = atomicAdd(&cursor[d], 1);
                colp[d * PAD + r] = s;
            }
        }
    } else if (b < FILL_BLOCKS + CVTX_BLOCKS) {
        int i = ((b - FILL_BLOCKS) * 256 + threadIdx.x) * 4;
        float4 v = *(const float4*)(x + i);
        uint2 o;
        o.x = (uint_t)f2bf(v.x) | ((uint_t)f2bf(v.y) << 16);
        o.y = (uint_t)f2bf(v.z) | ((uint_t)f2bf(v.w) << 16);
        *(uint2*)(h + i) = o;
    } else {
        int idx = (b - FILL_BLOCKS - CVTX_BLOCKS) * 256 + threadIdx.x;  // 0..81919
        if (idx < 65536) {
            const float* Ws = (idx < 32768) ? ws0 : ws1;
            const float* Wn = (idx < 32768) ? wn0 : wn1;
            ushort_t* Wt    = (idx < 32768) ? wt0 : wt1;
            int local = idx & 32767;
            int n = local >> 8, k = local & 255;
            float v = (k < 128) ? Ws[k * 128 + n] : Wn[(k - 128) * 128 + n];
            Wt[n * 256 + k] = f2bf(v);
        } else {
            int local = idx - 65536;                // 16384 elems
            int n = local >> 7, k = local & 127;
            float v = (n < 64) ? ws2[k * 64 + n] : wn2[k * 64 + (n - 64)];
            wt2[n * 128 + k] = f2bf(v);
        }
    }
}

// ======== gather-mean, 128-wide rows, dwordx4: 4 edges/load, 16 in flight ====
// lane = j*16 + d: j = edge slot (0..3), d = 16B chunk (feats d*8..d*8+7).

__global__ __launch_bounds__(256) void k_agg(const ushort_t* __restrict__ h,
                                             const int* __restrict__ cur,
                                             const int* __restrict__ colp,
                                             ushort_t* __restrict__ out) {
    const int node = blockIdx.x * 4 + (threadIdx.x >> 6);   // 25000*4 == N
    const int lane = threadIdx.x & 63;
    const int j = lane >> 4;
    const int d = lane & 15;
    const int beg = node * PAD;
    const int deg = cur[node];
    const int end = beg + deg;
    float acc[8];
#pragma unroll
    for (int k = 0; k < 8; ++k) acc[k] = 0.f;

    int i = beg;
    for (; i + 16 <= end; i += 16) {        // 4 quads in flight
        int c0 = colp[i + j];
        int c1 = colp[i + 4 + j];
        int c2 = colp[i + 8 + j];
        int c3 = colp[i + 12 + j];
        uint4 v0 = *(const uint4*)(h + (size_t)c0 * 128 + d * 8);
        uint4 v1 = *(const uint4*)(h + (size_t)c1 * 128 + d * 8);
        uint4 v2 = *(const uint4*)(h + (size_t)c2 * 128 + d * 8);
        uint4 v3 = *(const uint4*)(h + (size_t)c3 * 128 + d * 8);
        UNPACK4(v0) UNPACK4(v1) UNPACK4(v2) UNPACK4(v3)
    }
    if (i + 8 <= end) {
        int c0 = colp[i + j];
        int c1 = colp[i + 4 + j];
        uint4 v0 = *(const uint4*)(h + (size_t)c0 * 128 + d * 8);
        uint4 v1 = *(const uint4*)(h + (size_t)c1 * 128 + d * 8);
        UNPACK4(v0) UNPACK4(v1)
        i += 8;
    }
    if (i + 4 <= end) {
        int c0 = colp[i + j];
        uint4 v0 = *(const uint4*)(h + (size_t)c0 * 128 + d * 8);
        UNPACK4(v0)
        i += 4;
    }
    int rem = end - i;                      // 0..3
    if (rem > 0) {
        int idx = i + (j < rem ? j : 0);    // clamped dup -> same line, L1 hit
        int c0 = colp[idx];
        uint4 v0 = *(const uint4*)(h + (size_t)c0 * 128 + d * 8);
        if (j < rem) { UNPACK4(v0) }
    }
#pragma unroll
    for (int k = 0; k < 8; ++k) {
        acc[k] += __shfl_xor(acc[k], 16);
        acc[k] += __shfl_xor(acc[k], 32);
    }
    float inv = (deg > 0) ? 1.0f / (float)deg : 0.f;
    if (lane < 16) {
        uint4 o;
        o.x = (uint_t)f2bf(acc[0] * inv) | ((uint_t)f2bf(acc[1] * inv) << 16);
        o.y = (uint_t)f2bf(acc[2] * inv) | ((uint_t)f2bf(acc[3] * inv) << 16);
        o.z = (uint_t)f2bf(acc[4] * inv) | ((uint_t)f2bf(acc[5] * inv) << 16);
        o.w = (uint_t)f2bf(acc[6] * inv) | ((uint_t)f2bf(acc[7] * inv) << 16);
        *(uint4*)(out + (size_t)node * 128 + d * 8) = o;
    }
}

// ======== gather-mean-add, 64-wide bf16 rows (128B): 8 edges/load ========
// lane = j*8 + d: j = edge slot (0..7), d = 16B chunk.

__global__ __launch_bounds__(256) void k_agg_add64(const ushort_t* __restrict__ g,
                                                   const int* __restrict__ cur,
                                                   const int* __restrict__ colp,
                                                   float* __restrict__ out) {
    const int node = blockIdx.x * 4 + (threadIdx.x >> 6);
    const int lane = threadIdx.x & 63;
    const int j = lane >> 3;
    const int d = lane & 7;
    const int beg = node * PAD;
    const int deg = cur[node];
    const int end = beg + deg;
    float acc[8];
#pragma unroll
    for (int k = 0; k < 8; ++k) acc[k] = 0.f;

    int i = beg;
    for (; i + 16 <= end; i += 16) {        // 2 in flight
        int c0 = colp[i + j];
        int c1 = colp[i + 8 + j];
        uint4 v0 = *(const uint4*)(g + (size_t)c0 * 64 + d * 8);
        uint4 v1 = *(const uint4*)(g + (size_t)c1 * 64 + d * 8);
        UNPACK4(v0) UNPACK4(v1)
    }
    if (i + 8 <= end) {
        int c0 = colp[i + j];
        uint4 v0 = *(const uint4*)(g + (size_t)c0 * 64 + d * 8);
        UNPACK4(v0)
        i += 8;
    }
    int rem = end - i;                      // 0..7
    if (rem > 0) {
        int idx = i + (j < rem ? j : 0);
        int c0 = colp[idx];
        uint4 v0 = *(const uint4*)(g + (size_t)c0 * 64 + d * 8);
        if (j < rem) { UNPACK4(v0) }
    }
#pragma unroll
    for (int k = 0; k < 8; ++k) {
        acc[k] += __shfl_xor(acc[k], 8);
        acc[k] += __shfl_xor(acc[k], 16);
        acc[k] += __shfl_xor(acc[k], 32);
    }
    float inv = (deg > 0) ? 1.0f / (float)deg : 0.f;
    if (lane < 8) {
        float* p = out + (size_t)node * 64 + d * 8;
        float4 p0 = *(float4*)p;
        float4 p1 = *(float4*)(p + 4);
        p0.x += acc[0] * inv; p0.y += acc[1] * inv;
        p0.z += acc[2] * inv; p0.w += acc[3] * inv;
        p1.x += acc[4] * inv; p1.y += acc[5] * inv;
        p1.z += acc[6] * inv; p1.w += acc[7] * inv;
        *(float4*)p = p0;
        *(float4*)(p + 4) = p1;
    }
}

// ======== dual-GEMM + bias + ReLU (layers 0,1): K=256, LDS weights ========
// 512 threads (8 waves)/block: 67.6KB LDS -> 2 blocks/CU = 16 waves/CU.

__global__ __launch_bounds__(512) void k_gemm(const ushort_t* __restrict__ hs,
                                              const ushort_t* __restrict__ hn,
                                              const ushort_t* __restrict__ wt,
                                              const float* __restrict__ bias,
                                              ushort_t* __restrict__ hout) {
    constexpr int NT = 8;
    __shared__ ushort_t lds_w[128][264];   // pitch 528B -> 2-way (free) conflicts
    const int t = threadIdx.x;
    for (int c = t; c < 128 * 32; c += 512) {
        int r = c >> 5, o = c & 31;
        *(uint4*)(&lds_w[r][o * 8]) = *(const uint4*)(wt + r * 256 + o * 8);
    }
    __syncthreads();

    int wid = t >> 6, lane = t & 63;
    int row0 = blockIdx.x * 128 + wid * 16;
    int arow = row0 + (lane & 15);
    if (arow >= N_NODES) arow = N_NODES - 1;
    int hi = lane >> 4;   // 0..3

    f32x4 acc[NT];
#pragma unroll
    for (int n = 0; n < NT; n++) acc[n] = (f32x4){0.f, 0.f, 0.f, 0.f};

#pragma unroll
    for (int kk = 0; kk < 8; kk++) {
        const ushort_t* hp = (kk < 4) ? hs : hn;
        int kloc = (kk & 3) * 32 + hi * 8;
        bf16x8 a = *(const bf16x8*)(hp + (size_t)arow * 128 + kloc);
#pragma unroll
        for (int n = 0; n < NT; n++) {
            bf16x8 b = *(const bf16x8*)(&lds_w[n * 16 + (lane & 15)][kk * 32 + hi * 8]);
            acc[n] = __builtin_amdgcn_mfma_f32_16x16x32_bf16(a, b, acc[n], 0, 0, 0);
        }
    }

#pragma unroll
    for (int n = 0; n < NT; n++) {
        int colc = n * 16 + (lane & 15);
        float bv = bias[colc];
#pragma unroll
        for (int j = 0; j < 4; j++) {
            int row = row0 + hi * 4 + j;
            if (row < N_NODES) {
                float v = acc[n][j] + bv;
                v = v > 0.f ? v : 0.f;
                hout[(size_t)row * 128 + colc] = f2bf(v);
            }
        }
    }
}

// ======== layer-2 GEMM: K=128, [s2=h@Ws2+b2 -> f32 d_out | g2=h@Wn2 -> bf16] ==

__global__ __launch_bounds__(512) void k_gemm2(const ushort_t* __restrict__ hs,
                                               const ushort_t* __restrict__ wt,
                                               const float* __restrict__ bias,
                                               float* __restrict__ fout,
                                               ushort_t* __restrict__ g2) {
    constexpr int NT = 8;
    __shared__ ushort_t lds_w[128][136];   // 34.8KB -> 4 blocks/CU
    const int t = threadIdx.x;
    for (int c = t; c < 128 * 16; c += 512) {
        int r = c >> 4, o = c & 15;
        *(uint4*)(&lds_w[r][o * 8]) = *(const uint4*)(wt + r * 128 + o * 8);
    }
    __syncthreads();

    int wid = t >> 6, lane = t & 63;
    int row0 = blockIdx.x * 128 + wid * 16;
    int arow = row0 + (lane & 15);
    if (arow >= N_NODES) arow = N_NODES - 1;
    int hi = lane >> 4;   // 0..3

    f32x4 acc[NT];
#pragma unroll
    for (int n = 0; n < NT; n++) acc[n] = (f32x4){0.f, 0.f, 0.f, 0.f};

#pragma unroll
    for (int kk = 0; kk < 4; kk++) {
        bf16x8 a = *(const bf16x8*)(hs + (size_t)arow * 128 + kk * 32 + hi * 8);
#pragma unroll
        for (int n = 0; n < NT; n++) {
            bf16x8 b = *(const bf16x8*)(&lds_w[n * 16 + (lane & 15)][kk * 32 + hi * 8]);
            acc[n] = __builtin_amdgcn_mfma_f32_16x16x32_bf16(a, b, acc[n], 0, 0, 0);
        }
    }

#pragma unroll
    for (int n = 0; n < NT; n++) {
        int colc = n * 16 + (lane & 15);    // 0..127
#pragma unroll
        for (int j = 0; j < 4; j++) {
            int row = row0 + hi * 4 + j;
            if (row < N_NODES) {
                float v = acc[n][j];
                if (n < 4) fout[(size_t)row * 64 + colc] = v + bias[colc];
                else       g2[(size_t)row * 64 + (colc - 64)] = f2bf(v);
            }
        }
    }
}

// ======== launch ========

extern "C" void kernel_launch(void* const* d_in, const int* in_sizes, int n_in,
                              void* d_out, int out_size, void* d_ws, size_t ws_size,
                              hipStream_t stream) {
    const float* x   = (const float*)d_in[0];
    const int*   src = (const int*)d_in[1];
    const int*   dst = (const int*)d_in[2];
    const float* ws0 = (const float*)d_in[3];
    const float* wn0 = (const float*)d_in[4];
    const float* b0  = (const float*)d_in[5];
    const float* ws1 = (const float*)d_in[6];
    const float* wn1 = (const float*)d_in[7];
    const float* b1  = (const float*)d_in[8];
    const float* ws2 = (const float*)d_in[9];
    const float* wn2 = (const float*)d_in[10];
    const float* b2  = (const float*)d_in[11];

    char* ws = (char*)d_ws;
    size_t o = 0;
    auto alloc = [&](size_t bytes) { size_t r = o; o = (o + bytes + 255) & ~(size_t)255; return r; };
    int* cursor     = (int*)(ws + alloc((size_t)N_NODES * 4));
    int* colp       = (int*)(ws + alloc((size_t)N_NODES * PAD * 4));   // 25.6MB padded CSR
    ushort_t* wt0   = (ushort_t*)(ws + alloc(128 * 256 * 2));
    ushort_t* wt1   = (ushort_t*)(ws + alloc(128 * 256 * 2));
    ushort_t* wt2   = (ushort_t*)(ws + alloc(128 * 128 * 2));
    ushort_t* hA    = (ushort_t*)(ws + alloc((size_t)N_NODES * 128 * 2));
    ushort_t* hB    = (ushort_t*)(ws + alloc((size_t)N_NODES * 128 * 2));
    ushort_t* hN    = (ushort_t*)(ws + alloc((size_t)N_NODES * 128 * 2));
    (void)ws_size;

    (void)hipMemsetAsync(cursor, 0, (size_t)N_NODES * 4, stream);
    k_pre<<<FILL_BLOCKS + CVTX_BLOCKS + CVTW_BLOCKS, 256, 0, stream>>>(
        src, dst, cursor, colp, x, hA, ws0, wn0, ws1, wn1, ws2, wn2, wt0, wt1, wt2);

    const int AGG_GRID  = N_NODES / 4;             // 25000
    const int GEMM_GRID = (N_NODES + 127) / 128;   // 782

    // layers 0,1: aggregate-then-project
    k_agg<<<AGG_GRID, 256, 0, stream>>>(hA, cursor, colp, hN);
    k_gemm<<<GEMM_GRID, 512, 0, stream>>>(hA, hN, wt0, b0, hB);
    k_agg<<<AGG_GRID, 256, 0, stream>>>(hB, cursor, colp, hN);
    k_gemm<<<GEMM_GRID, 512, 0, stream>>>(hB, hN, wt1, b1, hA);
    // layer 2: project-then-aggregate (64-wide gather)
    k_gemm2<<<GEMM_GRID, 512, 0, stream>>>(hA, wt2, b2, (float*)d_out, hN);
    k_agg_add64<<<AGG_GRID, 256, 0, stream>>>(hN, cursor, colp, (float*)d_out);
}